// Round 11
// baseline (119.757 us; speedup 1.0000x reference)
//
#include <hip/hip_runtime.h>
#include <math.h>

#define D_MODEL 32
#define S_LEN   2048
#define B_SZ    8
#define NTOK    (B_SZ * S_LEN)
#define LN_EPS  1e-5f
#define LOG2E   1.44269504088896340736f
#define QK_SCALE 0.35355339059327373f   /* 1/sqrt(8) */
#define MASKV   (-1.0e9f)               /* v_exp_f32(-1e9) == 0 */

typedef __attribute__((ext_vector_type(8)))  short    short8b;
typedef __attribute__((ext_vector_type(4)))  short    short4b;
typedef __attribute__((ext_vector_type(4)))  unsigned uint4v;
typedef __attribute__((ext_vector_type(16))) float    f32x16;

__device__ __forceinline__ unsigned short f2bf(float f) {   // RNE f32->bf16
    unsigned u = __builtin_bit_cast(unsigned, f);
    unsigned r = (u + 0x7FFFu + ((u >> 16) & 1u)) >> 16;
    return (unsigned short)r;
}
__device__ __forceinline__ float bf2f(unsigned short h) {
    return __builtin_bit_cast(float, (unsigned)h << 16);
}
__device__ __forceinline__ unsigned cvtpk_bf16(float lo, float hi) {
    unsigned r;
    asm("v_cvt_pk_bf16_f32 %0, %1, %2" : "=v"(r) : "v"(lo), "v"(hi));
    return r;
}

// ---------------------------------------------------------------------------
// QKV projection. Q (pre-scaled by 1/sqrt(8)*log2e) and K are stored as
// SPLIT bf16 (hi = bf16(x), lo = bf16(x - hi)) so QK^T can be computed
// exactly with two MFMAs. V stored transposed per head, single bf16.
__global__ __launch_bounds__(256) void proj_kernel(
    const float* __restrict__ xQ, const float* __restrict__ xK,
    const float* __restrict__ xV,
    const float* __restrict__ WQ, const float* __restrict__ bQ,
    const float* __restrict__ WK, const float* __restrict__ bK,
    const float* __restrict__ WV, const float* __restrict__ bV,
    unsigned short* __restrict__ Qh, unsigned short* __restrict__ Ql,
    unsigned short* __restrict__ Kh, unsigned short* __restrict__ Kl,
    unsigned short* __restrict__ Vt)
{
    const float* x; const float* W; const float* bias; float scale;
    if (blockIdx.y == 0)      { x = xQ; W = WQ; bias = bQ; scale = QK_SCALE * LOG2E; }
    else if (blockIdx.y == 1) { x = xK; W = WK; bias = bK; scale = 1.0f; }
    else                      { x = xV; W = WV; bias = bV; scale = 1.0f; }

    __shared__ float xs[8][32];
    __shared__ float Ws[32][32];
    int t = threadIdx.x;
    long base = (long)blockIdx.x * 256;    // 8 rows x 32 cols
    xs[t >> 5][t & 31] = x[base + t];
#pragma unroll
    for (int i = 0; i < 4; ++i) {
        int f = i * 256 + t;
        Ws[f >> 5][f & 31] = W[f];
    }
    __syncthreads();
    int r = t >> 5, j = t & 31;
    float acc = bias[j];
#pragma unroll
    for (int i = 0; i < 32; ++i) acc = fmaf(xs[r][i], Ws[i][j], acc);
    acc *= scale;

    if (blockIdx.y == 0) {
        unsigned short hv = f2bf(acc);
        Qh[base + t] = hv;
        Ql[base + t] = f2bf(acc - bf2f(hv));
    } else if (blockIdx.y == 1) {
        unsigned short hv = f2bf(acc);
        Kh[base + t] = hv;
        Kl[base + t] = f2bf(acc - bf2f(hv));
    } else {
        long tok = (long)blockIdx.x * 8 + r;
        long b   = tok >> 11;
        long ti  = tok & (S_LEN - 1);
        int  h   = j >> 3, dv = j & 7;
        Vt[((b * 4 + h) * 8 + dv) * S_LEN + ti] = f2bf(acc);
    }
}

// ---------------------------------------------------------------------------
// MFMA flash attention with FUSED raw-mask read (no-max, exp2 domain, split-K,
// exact QK via split-bf16). Wave = (b, seg, 32-q tile). Per 32-key chunk:
//   lane q loads mask[tokq][kc..kc+31] raw (8x dwordx4, one 128B line);
//   then per head: 2 QK MFMA -> exp2(sel(acc, -1e9)) -> cvt_pk bf16 ->
//   2 PV MFMA (V^T A-frags mirror P's (half,elem)->key mapping).
// Arithmetic per output is identical to the verified R10 kernel.
template<int NSEG, bool I32>
__device__ __forceinline__ void attn_body(
    int b, int seg, int qt, int lane,
    const unsigned short* __restrict__ Qh, const unsigned short* __restrict__ Ql,
    const unsigned short* __restrict__ Kh, const unsigned short* __restrict__ Kl,
    const unsigned short* __restrict__ Vt, const void* __restrict__ mask,
    float* __restrict__ pl, float* __restrict__ pctx)
{
    constexpr int SEGLEN = S_LEN / NSEG;
    constexpr int NCH    = SEGLEN / 32;
    int q     = lane & 31;
    int half  = lane >> 5;
    int tok0  = qt * 32;
    long tokq = (long)b * S_LEN + tok0 + q;
    int k0    = seg * SEGLEN;

    f32x16 zero16;
#pragma unroll
    for (int i = 0; i < 16; ++i) zero16[i] = 0.0f;

    short8b qhf[4], qlf[4];
#pragma unroll
    for (int h = 0; h < 4; ++h) {
        qhf[h] = *(const short8b*)(Qh + tokq * 32 + h * 8);
        qlf[h] = *(const short8b*)(Ql + tokq * 32 + h * 8);
    }
    f32x16 cpv[4];
#pragma unroll
    for (int h = 0; h < 4; ++h) cpv[h] = zero16;

    const unsigned short* Ksel = (half ? Kl : Kh) + (long)b * S_LEN * 32;
    const int*  mrow32 = (const int*)mask + tokq * S_LEN;
    const int4* mrow8  = (const int4*)((const unsigned char*)mask + tokq * S_LEN);

#pragma unroll 1
    for (int ch = 0; ch < NCH; ++ch) {
        int kc = k0 + ch * 32;

        // ---- raw mask chunk for this lane's row: keys kc..kc+31
        int4 mm[8];
        if (I32) {
            const int4* mp = (const int4*)(mrow32 + kc);
#pragma unroll
            for (int i = 0; i < 8; ++i) mm[i] = mp[i];
        } else {
            mm[0] = mrow8[(kc >> 4)];
            mm[1] = mrow8[(kc >> 4) + 1];
        }

#pragma unroll
        for (int h = 0; h < 4; ++h) {
            // A rows m=lane&31 -> key kc+q; half0 supplies K_hi (k-slots 0-7),
            // half1 supplies K_lo (k-slots 8-15), both at d0-7 of head h.
            short8b kf = *(const short8b*)(Ksel + (long)(kc + q) * 32 + h * 8);
            f32x16 acc = __builtin_amdgcn_mfma_f32_32x32x16_bf16(kf, qhf[h], zero16, 0, 0, 0);
            acc = __builtin_amdgcn_mfma_f32_32x32x16_bf16(kf, qlf[h], acc, 0, 0, 0);

            unsigned pr[8];
#pragma unroll
            for (int j = 0; j < 8; ++j) {
                float s0, s1;
#pragma unroll
                for (int e = 0; e < 2; ++e) {
                    int r = 2 * j + e;
                    int key = (r & 3) + 8 * (r >> 2) + 4 * half;   // C/D row formula
                    int mv;
                    if (I32) {
                        int4 w4 = mm[key >> 2];
                        int  wi = (key & 3) == 0 ? w4.x : (key & 3) == 1 ? w4.y
                                 : (key & 3) == 2 ? w4.z : w4.w;
                        mv = (wi != 0);
                    } else {
                        int4 w4 = mm[key >> 4];
                        int  sub = (key >> 2) & 3;
                        int  wi = sub == 0 ? w4.x : sub == 1 ? w4.y
                                 : sub == 2 ? w4.z : w4.w;
                        mv = ((wi >> (8 * (key & 3))) & 255) != 0;
                    }
                    float sv = mv ? MASKV : acc[r];
                    if (e == 0) s0 = sv; else s1 = sv;
                }
                pr[j] = cvtpk_bf16(__builtin_amdgcn_exp2f(s0),
                                   __builtin_amdgcn_exp2f(s1));
            }
            uint4v t1, t2;
            t1.x = pr[0]; t1.y = pr[1]; t1.z = pr[2]; t1.w = pr[3];
            t2.x = pr[4]; t2.y = pr[5]; t2.z = pr[6]; t2.w = pr[7];
            short8b pfa = __builtin_bit_cast(short8b, t1);
            short8b pfb = __builtin_bit_cast(short8b, t2);

            // V^T A-frags mirror P's (half, elem)->key mapping exactly, so the
            // shared k-slot permutation cancels regardless of HW slot order.
            short8b vf1, vf2;
            if (q < 8) {
                const unsigned short* vr =
                    Vt + (((long)b * 4 + h) * 8 + q) * S_LEN + kc + half * 4;
                short4b a0 = *(const short4b*)(vr);
                short4b a1 = *(const short4b*)(vr + 8);
                short4b a2 = *(const short4b*)(vr + 16);
                short4b a3 = *(const short4b*)(vr + 24);
                vf1 = __builtin_shufflevector(a0, a1, 0, 1, 2, 3, 4, 5, 6, 7);
                vf2 = __builtin_shufflevector(a2, a3, 0, 1, 2, 3, 4, 5, 6, 7);
            } else {
                short ov = (q == 8) ? (short)0x3F80 : (short)0;  // ones row -> l-sum
#pragma unroll
                for (int i = 0; i < 8; ++i) { vf1[i] = ov; vf2[i] = ov; }
            }
            cpv[h] = __builtin_amdgcn_mfma_f32_32x32x16_bf16(vf1, pfa, cpv[h], 0, 0, 0);
            cpv[h] = __builtin_amdgcn_mfma_f32_32x32x16_bf16(vf2, pfb, cpv[h], 0, 0, 0);
        }
    }

    // C_PV: col=q; lower half regs0-3 = dv0-3, reg4 = row8 = l-sum;
    // upper half regs0-3 = dv4-7.
#pragma unroll
    for (int h = 0; h < 4; ++h) {
        float4 cv = make_float4(cpv[h][0], cpv[h][1], cpv[h][2], cpv[h][3]);
        *(float4*)(pctx + ((size_t)seg * NTOK + tokq) * 32 + h * 8 + half * 4) = cv;
        if (half == 0)
            pl[(size_t)seg * NTOK * 4 + tokq * 4 + h] = cpv[h][4];
    }
}

template<int NSEG>
__global__ __launch_bounds__(256) void attn_kernel(
    const unsigned short* __restrict__ Qh, const unsigned short* __restrict__ Ql,
    const unsigned short* __restrict__ Kh, const unsigned short* __restrict__ Kl,
    const unsigned short* __restrict__ Vt, const void* __restrict__ mask,
    float* __restrict__ pl, float* __restrict__ pctx)
{
    const int nb    = NSEG * 16;            // blocks per batch (4 waves/block)
    int raw   = blockIdx.x;
    int total = B_SZ * nb;
    int cpx   = total >> 3;
    int cid   = (raw & 7) * cpx + (raw >> 3);   // XCD-contiguous
    int b     = cid / nb;
    int rem   = cid - b * nb;
    int seg   = rem >> 4;
    int qt    = (rem & 15) * 4 + (threadIdx.x >> 6);
    int lane  = threadIdx.x & 63;

    // inline dtype probe: int32 layout => upper 3 bytes of first 64 words zero
    int probe  = ((const int*)mask)[lane];
    int okp    = ((probe & ~0xFF) == 0);
    bool is32  = (__ballot(okp) == ~0ULL);

    if (is32)
        attn_body<NSEG, true >(b, seg, qt, lane, Qh, Ql, Kh, Kl, Vt, mask, pl, pctx);
    else
        attn_body<NSEG, false>(b, seg, qt, lane, Qh, Ql, Kh, Kl, Vt, mask, pl, pctx);
}

// ---------------------------------------------------------------------------
// Merge split-K partials (plain sums) -> sa; attn_out = sa@WO + bO + resid; LN.
template<int NSEG>
__global__ __launch_bounds__(256) void combine_epilogue(
    const float* __restrict__ pl, const float* __restrict__ pctx,
    const float* __restrict__ WO, const float* __restrict__ bO,
    const float* __restrict__ resid,
    float* __restrict__ sa_out, float* __restrict__ out0)
{
    __shared__ float sas[8][32];
    __shared__ float Ws[32][32];
    int t = threadIdx.x;
    long base = (long)blockIdx.x * 256;      // 8 tokens x 32
    int r = t >> 5, j = t & 31;
    long tok = (long)blockIdx.x * 8 + r;
    int h = j >> 3;

#pragma unroll
    for (int i = 0; i < 4; ++i) {
        int f = i * 256 + t;
        Ws[f >> 5][f & 31] = WO[f];
    }

    float L = 0.f, ctx = 0.f;
#pragma unroll
    for (int s2 = 0; s2 < NSEG; ++s2) {
        L   += pl[(size_t)s2 * NTOK * 4 + tok * 4 + h];
        ctx += pctx[((size_t)s2 * NTOK + tok) * 32 + j];
    }
    float sa = ctx / L;
    sa_out[base + t] = sa;
    sas[r][j] = sa;
    __syncthreads();

    float y = bO[j] + resid[base + t];
#pragma unroll
    for (int i = 0; i < 32; ++i) y = fmaf(sas[r][i], Ws[i][j], y);

    float sum = y;
#pragma unroll
    for (int o = 16; o >= 1; o >>= 1) sum += __shfl_xor(sum, o, 32);
    float mu = sum * (1.0f / 32.0f);
    float d  = y - mu;
    float sq = d * d;
#pragma unroll
    for (int o = 16; o >= 1; o >>= 1) sq += __shfl_xor(sq, o, 32);
    float var = sq * (1.0f / 32.0f);
    out0[base + t] = d * rsqrtf(var + LN_EPS);
}

// ---------------------------------------------------------------------------
extern "C" void kernel_launch(void* const* d_in, const int* in_sizes, int n_in,
                              void* d_out, int out_size, void* d_ws, size_t ws_size,
                              hipStream_t stream)
{
    const float* inQ = (const float*)d_in[0];
    const float* inK = (const float*)d_in[1];
    const float* inV = (const float*)d_in[2];
    const void*  mask = d_in[3];
    const float* WQ = (const float*)d_in[4];
    const float* bQ = (const float*)d_in[5];
    const float* WK = (const float*)d_in[6];
    const float* bK = (const float*)d_in[7];
    const float* WV = (const float*)d_in[8];
    const float* bV = (const float*)d_in[9];
    const float* WO = (const float*)d_in[10];
    const float* bO = (const float*)d_in[11];

    float* out0 = (float*)d_out;                    // layernorm output
    float* sa   = (float*)d_out + (long)NTOK * 32;  // self_attn output

    char* ws = (char*)d_ws;
    unsigned short* Qh = (unsigned short*)(ws + 256);
    unsigned short* Ql = Qh + (long)NTOK * 32;
    unsigned short* Kh = Ql + (long)NTOK * 32;
    unsigned short* Kl = Kh + (long)NTOK * 32;
    unsigned short* Vt = Kl + (long)NTOK * 32;
    float* pbase = (float*)(Vt + (long)NTOK * 32);

    size_t fixed  = 256 + 5ul * NTOK * 32 * 2;
    size_t perseg = (size_t)NTOK * 36 * 4;
    int NS = 1;
    if      (fixed + 8 * perseg <= ws_size) NS = 8;
    else if (fixed + 4 * perseg <= ws_size) NS = 4;
    else if (fixed + 2 * perseg <= ws_size) NS = 2;

    float* pl   = pbase;
    float* pctx = pl + (long)NS * NTOK * 4;

    proj_kernel<<<dim3(NTOK / 8, 3), 256, 0, stream>>>(
        inQ, inK, inV, WQ, bQ, WK, bK, WV, bV, Qh, Ql, Kh, Kl, Vt);

    int agrid = B_SZ * NS * 16;
    int cgrid = NTOK / 8;
    switch (NS) {
    case 8:
        attn_kernel<8><<<agrid, 256, 0, stream>>>(Qh, Ql, Kh, Kl, Vt, mask, pl, pctx);
        combine_epilogue<8><<<cgrid, 256, 0, stream>>>(pl, pctx, WO, bO, inQ, sa, out0);
        break;
    case 4:
        attn_kernel<4><<<agrid, 256, 0, stream>>>(Qh, Ql, Kh, Kl, Vt, mask, pl, pctx);
        combine_epilogue<4><<<cgrid, 256, 0, stream>>>(pl, pctx, WO, bO, inQ, sa, out0);
        break;
    case 2:
        attn_kernel<2><<<agrid, 256, 0, stream>>>(Qh, Ql, Kh, Kl, Vt, mask, pl, pctx);
        combine_epilogue<2><<<cgrid, 256, 0, stream>>>(pl, pctx, WO, bO, inQ, sa, out0);
        break;
    default:
        attn_kernel<1><<<agrid, 256, 0, stream>>>(Qh, Ql, Kh, Kl, Vt, mask, pl, pctx);
        combine_epilogue<1><<<cgrid, 256, 0, stream>>>(pl, pctx, WO, bO, inQ, sa, out0);
        break;
    }
}